// Round 5
// baseline (866886.621 us; speedup 1.0000x reference)
//
#include <hip/hip_runtime.h>

// BiLSTM + partial-CRF loss, MI355X (gfx950).
// R5 = R4 hang-hardened. (1) sync groups pinned to XCDs (group = wid&7,
// runtime-verified via numeric hwreg(20,0,4)=XCC_ID handshake; consistent
// fallback to MALL-scope protocol if the round-robin mapping doesn't hold)
// -> h/flag traffic at per-XCD L2 (sc0) instead of MALL. (2) K-split across
// the 4 waves (each wave: all 4 gates, one K-quarter; LDS partial-sum) ->
// h-tile reads per wg/step 64KB -> 16KB. (3) ALL polls hard-budgeted:
// worst case terminates with wrong output instead of watchdog hang.
//
// Sizes: B=64, L=512, V=50000, E=256, H=512, T=32.
// Workspace (~84 MiB):
//   x2  bf16 [512*64][256]    16777216 B @ 0
//   H2  bf16 [512*64][1024]   67108864 B @ 16777216   (hf|hb)
//   em  f32  [512*64][32]      4194304 B @ 83886080
//   flg int  [8 groups][32][16] + tbl int[256]  @ 88080384

#define IMPOSSIBLE -10000.0f

typedef __attribute__((ext_vector_type(8))) short bf16x8;
typedef __attribute__((ext_vector_type(4))) float f32x4;
typedef unsigned int u32;
typedef unsigned short u16;

__device__ __forceinline__ u16 f2b(float f) {           // fp32 -> bf16 (RNE)
  union { float f; u32 u; } v; v.f = f;
  return (u16)((v.u + 0x7fffu + ((v.u >> 16) & 1u)) >> 16);
}
__device__ __forceinline__ float sigm(float x) { return 1.0f / (1.0f + __expf(-x)); }
__device__ __forceinline__ float tanh_f(float x) { return 1.0f - 2.0f / (__expf(2.0f * x) + 1.0f); }

// Scoped flag/data ops. mall=false: sc0 (bypass L1, coherent in per-XCD L2).
// mall=true: agent atomics (coherent at MALL) -- the R3 protocol.
__device__ __forceinline__ void st_u32(u32* p, u32 v, bool mall) {
  if (mall) __hip_atomic_store(p, v, __ATOMIC_RELAXED, __HIP_MEMORY_SCOPE_AGENT);
  else asm volatile("global_store_dword %0, %1, off sc0" :: "v"(p), "v"(v) : "memory");
}
__device__ __forceinline__ u32 ld_u32(const u32* p, bool mall) {
  u32 v;
  if (mall) v = __hip_atomic_load(p, __ATOMIC_RELAXED, __HIP_MEMORY_SCOPE_AGENT);
  else asm volatile("global_load_dword %0, %1, off sc0\n\ts_waitcnt vmcnt(0)"
                    : "=v"(v) : "v"(p) : "memory");
  return v;
}

// ---------------------------------------------------------------------------
// flags=0 + xcd-table=-1 + out=0, all MALL-visible stores.
__global__ void k_init(int* __restrict__ flg, float* __restrict__ out) {
  const int i = blockIdx.x * 256 + threadIdx.x;
  if (i < 4096)
    __hip_atomic_store(flg + i, 0, __ATOMIC_RELAXED, __HIP_MEMORY_SCOPE_AGENT);
  else if (i < 4352)
    __hip_atomic_store(flg + i, -1, __ATOMIC_RELAXED, __HIP_MEMORY_SCOPE_AGENT);
  if (i == 0)
    __hip_atomic_store((u32*)out, 0u, __ATOMIC_RELAXED, __HIP_MEMORY_SCOPE_AGENT);
}

// ---------------------------------------------------------------------------
// x2[t*64+b][e] = bf16(emb[sents[b][t]][e]).  One block per t.
__global__ __launch_bounds__(256) void k_embed(
    const int* __restrict__ sents, const float* __restrict__ emb,
    u16* __restrict__ x2) {
  __shared__ int tok[64];
  const int tid = threadIdx.x, t = blockIdx.x;
  if (tid < 64) tok[tid] = sents[tid * 512 + t];
  __syncthreads();
#pragma unroll
  for (int i = 0; i < 16; ++i) {
    const int v = i * 256 + tid;          // float4 index
    const int row = v >> 6, ke = (v & 63) * 4;
    const float4 f = *(const float4*)(emb + (size_t)tok[row] * 256 + ke);
    ushort4 s; s.x = f2b(f.x); s.y = f2b(f.y); s.z = f2b(f.z); s.w = f2b(f.w);
    *(ushort4*)&x2[((size_t)t * 64 + row) * 256 + ke] = s;
  }
}

// ---------------------------------------------------------------------------
// Persistent BiLSTM. 256 wgs x 256 thr, 1 wg/CU. group r=wid&7 -> (d=r>>2,
// g=r&3); slice s=wid>>3 (j0=s*16). Wave wv owns K-quarter for ALL 4 gates.
// Whh/Wih B-frags in registers. Per step: issue x loads -> poll 32 group
// flags (budget 1<<14) -> x+h MFMAs -> LDS 4-way K-reduce -> gates ->
// h store (scoped) -> waitcnt+barrier -> flag store (scoped).
__global__ __launch_bounds__(256, 1) void k_lstm(
    const float* __restrict__ Whf, const float* __restrict__ Whb,
    const float* __restrict__ Wif, const float* __restrict__ Wib,
    const float* __restrict__ bf_, const float* __restrict__ bb_,
    const u16* __restrict__ x2, u16* __restrict__ H2, int* __restrict__ flg) {
  __shared__ float pre4[4 * 4 * 256];   // [wv][gate][b][j]
  __shared__ int fast_sh;
  const int tid = threadIdx.x, wid = blockIdx.x;
  const int r = wid & 7, d = r >> 2, g = r & 3, s = wid >> 3;
  const int b0 = g * 16, j0 = s * 16;
  const float* __restrict__ Whh = d ? Whb : Whf;
  const float* __restrict__ Wih = d ? Wib : Wif;
  const float* __restrict__ bias = d ? bb_ : bf_;
  const int wv = tid >> 6, lane = tid & 63, lm = lane & 15, kh = lane >> 4;
  const int bl = tid >> 4, jj = tid & 15;
  int* tbl = flg + 4096;

  // ---- XCD discovery: is the whole group (wid = r+8*s') on my XCD? ----
  int xcc;
  asm volatile("s_getreg_b32 %0, hwreg(20, 0, 4)" : "=s"(xcc));  // HW_REG_XCC_ID
  xcc &= 0xf;
  if (tid == 0) st_u32((u32*)(tbl + wid), (u32)xcc, true);
  bool ok = true;
  if (tid < 32) {
    const u32* pp = (const u32*)(tbl + r + tid * 8);
    int bud = 1 << 20;
    u32 v;
    do { v = ld_u32(pp, true); } while ((int)v < 0 && --bud);
    ok = ((int)v == xcc);
  }
  if (tid < 64) {
    unsigned long long mask = __ballot(ok);
    if (tid == 0) fast_sh = (mask == ~0ull) ? 1 : 0;
  }
  __syncthreads();
  const bool mall = (fast_sh == 0);     // fallback: MALL-scope protocol

  // ---- weight fragments: B[k][n], n=lane&15, k = kh*8+j + 32*kt + wv*Kq ----
  bf16x8 wih_f[8], whh_f[16];
#pragma unroll
  for (int gg = 0; gg < 4; ++gg) {
    const float* wp = Wih + (size_t)(gg * 512 + j0 + lm) * 256 + wv * 64;
#pragma unroll
    for (int kt = 0; kt < 2; ++kt) {
      bf16x8 f;
#pragma unroll
      for (int j = 0; j < 8; ++j) f[j] = (short)f2b(wp[kt * 32 + kh * 8 + j]);
      wih_f[gg * 2 + kt] = f;
    }
    const float* wq = Whh + (size_t)(gg * 512 + j0 + lm) * 512 + wv * 128;
#pragma unroll
    for (int kt = 0; kt < 4; ++kt) {
      bf16x8 f;
#pragma unroll
      for (int j = 0; j < 8; ++j) f[j] = (short)f2b(wq[kt * 32 + kh * 8 + j]);
      whh_f[gg * 4 + kt] = f;
    }
  }
  const float b_i = bias[0 * 512 + j0 + jj];
  const float b_f = bias[1 * 512 + j0 + jj];
  const float b_g = bias[2 * 512 + j0 + jj];
  const float b_o = bias[3 * 512 + j0 + jj];

  int* gflg = flg + (size_t)r * 512;    // 32 flags, 64B apart
  float c = 0.f;
  const f32x4 z = {0.f, 0.f, 0.f, 0.f};
#pragma unroll 1
  for (int it = 0; it < 512; ++it) {
    const int tt = d ? (511 - it) : it;
    // x a-frags (K-quarter): issue now, land during the poll
    bf16x8 xa[2];
    {
      const u16* xp = x2 + ((size_t)tt * 64 + b0 + lm) * 256 + wv * 64 + kh * 8;
      xa[0] = *(const bf16x8*)xp;
      xa[1] = *(const bf16x8*)(xp + 32);
    }
    if (it > 0) {
      if (tid < 32) {
        const u32* fp = (const u32*)(gflg + tid * 16);
        int bud = 1 << 14;   // normal detect <10 polls; hard bound vs hang
        while (ld_u32(fp, mall) < (u32)it && --bud) {}
      }
      __syncthreads();
    }
    f32x4 accg[4] = {z, z, z, z};
#pragma unroll
    for (int gg = 0; gg < 4; ++gg)
#pragma unroll
      for (int kt = 0; kt < 2; ++kt)
        accg[gg] = __builtin_amdgcn_mfma_f32_16x16x32_bf16(xa[kt], wih_f[gg * 2 + kt], accg[gg], 0, 0, 0);
    if (it > 0) {
      const int tp = d ? (tt + 1) : (tt - 1);
      const u16* hp = H2 + ((size_t)tp * 64 + b0 + lm) * 1024 + d * 512 + wv * 128 + kh * 8;
      bf16x8 ha[4];
#pragma unroll
      for (int kt = 0; kt < 4; ++kt) ha[kt] = *(const bf16x8*)(hp + kt * 32);
#pragma unroll
      for (int gg = 0; gg < 4; ++gg)
#pragma unroll
        for (int kt = 0; kt < 4; ++kt)
          accg[gg] = __builtin_amdgcn_mfma_f32_16x16x32_bf16(ha[kt], whh_f[gg * 4 + kt], accg[gg], 0, 0, 0);
    }
    // C layout: col(=j)=lm, row(=batch)=kh*4+rr. Partial sums -> LDS.
#pragma unroll
    for (int gg = 0; gg < 4; ++gg)
#pragma unroll
      for (int rr = 0; rr < 4; ++rr)
        pre4[wv * 1024 + gg * 256 + (kh * 4 + rr) * 16 + lm] = accg[gg][rr];
    __syncthreads();
    float pi = b_i, pf = b_f, pg = b_g, po = b_o;
#pragma unroll
    for (int w = 0; w < 4; ++w) {
      pi += pre4[w * 1024 + 0   + bl * 16 + jj];
      pf += pre4[w * 1024 + 256 + bl * 16 + jj];
      pg += pre4[w * 1024 + 512 + bl * 16 + jj];
      po += pre4[w * 1024 + 768 + bl * 16 + jj];
    }
    c = sigm(pf) * c + sigm(pi) * tanh_f(pg);
    const float h = sigm(po) * tanh_f(c);
    const float hpart = __shfl_xor(h, 1);
    if ((jj & 1) == 0) {    // pack (jj, jj+1) -> one u32, scoped store
      const u32 pk = (u32)f2b(h) | ((u32)f2b(hpart) << 16);
      const size_t idx = ((size_t)tt * 64 + b0 + bl) * 512 + (size_t)d * 256 + ((j0 + jj) >> 1);
      st_u32((u32*)H2 + idx, pk, mall);
    }
    asm volatile("s_waitcnt vmcnt(0)" ::: "memory");  // drain THIS wave's h stores
    __syncthreads();                                  // => all waves drained
    if (tid == 0) st_u32((u32*)(gflg + s * 16), (u32)(it + 1), mall);
  }
}

// ---------------------------------------------------------------------------
// em[t*64+b][tag] = [hf|hb] @ W_out^T + b_out.  One block per t (M=64,N=32,K=1024).
__global__ __launch_bounds__(256) void k_emproj(
    const u16* __restrict__ H2, const float* __restrict__ Wo,
    const float* __restrict__ bo, float* __restrict__ em) {
  __shared__ u16 Wl[32 * 1024];
  const int tid = threadIdx.x, mb = blockIdx.x;
  const int wv = tid >> 6, lane = tid & 63, lm = lane & 15, kh = lane >> 4;
#pragma unroll
  for (int i = 0; i < 32; ++i) {        // stage Wo 32x1024 f32 -> bf16, rotated
    const int row = i, k = tid * 4;
    const float4 f = *(const float4*)(Wo + (size_t)row * 1024 + k);
    ushort4 s; s.x = f2b(f.x); s.y = f2b(f.y); s.z = f2b(f.z); s.w = f2b(f.w);
    *(ushort4*)&Wl[row * 1024 + ((k + 8 * row) & 1023)] = s;
  }
  __syncthreads();
  const f32x4 z = {0.f, 0.f, 0.f, 0.f};
  f32x4 acc[2] = {z, z};
  const u16* ap = H2 + ((size_t)mb * 64 + wv * 16 + lm) * 1024 + kh * 8;
#pragma unroll 2
  for (int kt = 0; kt < 32; ++kt) {
    const bf16x8 a = *(const bf16x8*)(ap + kt * 32);
#pragma unroll
    for (int ni = 0; ni < 2; ++ni) {
      const int row = ni * 16 + lm;
      const bf16x8 b = *(const bf16x8*)&Wl[row * 1024 + ((kt * 32 + kh * 8 + 8 * row) & 1023)];
      acc[ni] = __builtin_amdgcn_mfma_f32_16x16x32_bf16(a, b, acc[ni], 0, 0, 0);
    }
  }
#pragma unroll
  for (int ni = 0; ni < 2; ++ni) {
    const int n = ni * 16 + lm;
    const float bv = bo[n];
#pragma unroll
    for (int rr = 0; rr < 4; ++rr) {
      const int m = mb * 64 + wv * 16 + kh * 4 + rr;
      em[(size_t)m * 32 + n] = acc[ni][rr] + bv;
    }
  }
}

// ---------------------------------------------------------------------------
// CRF forward scans, fp32. One wave per (b, which); halves merged via
// shfl_xor(32); t+1 prefetch; final reduction via atomicAdd(out).
__global__ __launch_bounds__(64) void k_crf(
    const float* __restrict__ em, const int* __restrict__ tgt,
    const float* __restrict__ trans, const float* __restrict__ stt,
    const float* __restrict__ ent, float* __restrict__ out) {
  __shared__ float trl[1024];
  __shared__ float al[32];
  __shared__ int cur[32];
  const int lane = threadIdx.x;
  const int b = blockIdx.x >> 1;
  const int isnum = blockIdx.x & 1;
#pragma unroll
  for (int i = 0; i < 16; ++i) trl[i * 64 + lane] = trans[i * 64 + lane];
  const int k = lane & 31, j0 = (lane >> 5) * 16;
  {
    float a0 = stt[k] + em[(size_t)b * 32 + k];
    int p0 = 1;
    if (isnum) { p0 = tgt[((size_t)b * 512) * 32 + k]; if (p0 == 0) a0 = IMPOSSIBLE; }
    if (lane < 32) { al[k] = a0; cur[k] = p0; }
  }
  __syncthreads();
  float emk = em[((size_t)64 + b) * 32 + k];                    // t=1 prefetch
  int tg = isnum ? tgt[((size_t)b * 512 + 1) * 32 + k] : 1;
#pragma unroll 1
  for (int t = 1; t < 512; ++t) {
    const float e_raw = emk;
    const int nxt = tg;
    if (t + 1 < 512) {                                          // prefetch t+1
      emk = em[((size_t)(t + 1) * 64 + b) * 32 + k];
      if (isnum) tg = tgt[((size_t)b * 512 + t + 1) * 32 + k];
    }
    const float e = (isnum && nxt == 0) ? IMPOSSIBLE : e_raw;
    float v[16];
    float m = -1e30f;
#pragma unroll
    for (int j = 0; j < 16; ++j) {
      float tr = trl[(j0 + j) * 32 + k];
      if (isnum && (cur[j0 + j] == 0 || nxt == 0)) tr = IMPOSSIBLE;
      v[j] = al[j0 + j] + tr;
      m = fmaxf(m, v[j]);
    }
    float ss = 0.f;
#pragma unroll
    for (int j = 0; j < 16; ++j) ss += __expf(v[j] - m);
    const float m2 = __shfl_xor(m, 32);
    const float s2 = __shfl_xor(ss, 32);
    const float M = fmaxf(m, m2);
    const float S = ss * __expf(m - M) + s2 * __expf(m2 - M);
    const float an = M + __logf(S) + e;
    __syncthreads();
    if (lane < 32) { al[k] = an; cur[k] = nxt; }
    __syncthreads();
  }
  float x;
  if (!isnum) {
    x = al[k] + ent[k];
  } else {
    const float et = ent[k] * (float)cur[k];
    x = al[k] + ((et == 0.f) ? IMPOSSIBLE : et);
  }
  float m = x;
#pragma unroll
  for (int o = 1; o < 32; o <<= 1) m = fmaxf(m, __shfl_xor(m, o));
  float ss = __expf(x - m);
#pragma unroll
  for (int o = 1; o < 32; o <<= 1) ss += __shfl_xor(ss, o);
  if (lane == 0) {
    const float rr = m + __logf(ss);
    atomicAdd(out, isnum ? -rr : rr);
  }
}

// ---------------------------------------------------------------------------
extern "C" void kernel_launch(void* const* d_in, const int* in_sizes, int n_in,
                              void* d_out, int out_size, void* d_ws, size_t ws_size,
                              hipStream_t stream) {
  (void)in_sizes; (void)n_in; (void)out_size; (void)ws_size;
  const int* sents = (const int*)d_in[0];
  const int* tgt = (const int*)d_in[2];
  const float* emb = (const float*)d_in[3];
  const float* Wif = (const float*)d_in[4];
  const float* Whf = (const float*)d_in[5];
  const float* bf_ = (const float*)d_in[6];
  const float* Wib = (const float*)d_in[7];
  const float* Whb = (const float*)d_in[8];
  const float* bb_ = (const float*)d_in[9];
  const float* Wo = (const float*)d_in[10];
  const float* bo = (const float*)d_in[11];
  const float* stt = (const float*)d_in[12];
  const float* ent = (const float*)d_in[13];
  const float* trans = (const float*)d_in[14];
  float* out = (float*)d_out;

  char* ws = (char*)d_ws;
  u16* x2 = (u16*)ws;                          // 16777216 B
  u16* H2 = (u16*)(ws + 16777216ull);          // 67108864 B
  float* em = (float*)(ws + 83886080ull);      //  4194304 B
  int* flg = (int*)(ws + 88080384ull);         //  flags 16KB + tbl 1KB

  k_init<<<dim3(17), dim3(256), 0, stream>>>(flg, out);
  k_embed<<<dim3(512), dim3(256), 0, stream>>>(sents, emb, x2);
  k_lstm<<<dim3(256), dim3(256), 0, stream>>>(Whf, Whb, Wif, Wib, bf_, bb_, x2, H2, flg);
  k_emproj<<<dim3(512), dim3(256), 0, stream>>>(H2, Wo, bo, em);
  k_crf<<<dim3(128), dim3(64), 0, stream>>>(em, tgt, trans, stt, ent, out);
}

// Round 6
// 218139.575 us; speedup vs baseline: 3.9740x; 3.9740x over previous
//
#include <hip/hip_runtime.h>

// BiLSTM + partial-CRF loss, MI355X (gfx950).
// R6: R5's hwreg-based XCD handshake gave a false positive -> sc0 polls spun
// on never-refreshed lines (1.76ms/step = poll budget). Now the fast path is
// gated by a COHERENCE ROUND-TRIP PROBE (leader sc0-store, members sc0-poll,
// MALL-voted consensus) that tests the actual sync mechanism; epoch from
// s_memrealtime makes flags immune to stale cross-launch lines and poison
// (signed compare). Blocked H2 layout (512B/producer/step), per-wave
// decoupled 8-flag polls, ds_write_b128 LDS partial sums.
//
// Sizes: B=64, L=512, V=50000, E=256, H=512, T=32.
// Workspace (~84 MiB):
//   x2   bf16 [512*64][256]                16777216 B @ 0
//   H2   bf16 blocked [t][d][g][s][bl][jj] 67108864 B @ 16777216
//   em   f32  [512*64][32]                  4194304 B @ 83886080
//   ctrl @ 88080384: flg u64[8][32] (64B apart) 16384 | probe u64[8] 512 |
//        rep u32[8] 512 | bad u32[8] 512 | epoch u64 @ +17920

#define IMPOSSIBLE -10000.0f

typedef __attribute__((ext_vector_type(8))) short bf16x8;
typedef __attribute__((ext_vector_type(4))) float f32x4;
typedef unsigned int u32;
typedef unsigned short u16;
typedef unsigned long long u64;
typedef long long i64;

__device__ __forceinline__ u16 f2b(float f) {           // fp32 -> bf16 (RNE)
  union { float f; u32 u; } v; v.f = f;
  return (u16)((v.u + 0x7fffu + ((v.u >> 16) & 1u)) >> 16);
}
__device__ __forceinline__ float sigm(float x) { return 1.0f / (1.0f + __expf(-x)); }
__device__ __forceinline__ float tanh_f(float x) { return 1.0f - 2.0f / (__expf(2.0f * x) + 1.0f); }

// Scoped ops. mall=true: agent atomics (bypass caches, MALL-coherent; R3-proven).
// mall=false: sc0 (XCD-L2 path; only used when the probe validated it).
__device__ __forceinline__ void st_u32s(u32* p, u32 v, bool mall) {
  if (mall) __hip_atomic_store(p, v, __ATOMIC_RELAXED, __HIP_MEMORY_SCOPE_AGENT);
  else asm volatile("global_store_dword %0, %1, off sc0" :: "v"(p), "v"(v) : "memory");
}
__device__ __forceinline__ void st_u64s(u64* p, u64 v, bool mall) {
  if (mall) __hip_atomic_store(p, v, __ATOMIC_RELAXED, __HIP_MEMORY_SCOPE_AGENT);
  else asm volatile("global_store_dwordx2 %0, %1, off sc0" :: "v"(p), "v"(v) : "memory");
}
__device__ __forceinline__ u64 ld_u64s(const u64* p, bool mall) {
  u64 v;
  if (mall) v = __hip_atomic_load(p, __ATOMIC_RELAXED, __HIP_MEMORY_SCOPE_AGENT);
  else asm volatile("global_load_dwordx2 %0, %1, off sc0\n\ts_waitcnt vmcnt(0)"
                    : "=v"(v) : "v"(p) : "memory");
  return v;
}

// ---------------------------------------------------------------------------
// ctrl zero (flags/probe/rep/bad = 4480 u32) + epoch + out, agent stores.
__global__ void k_init(u32* __restrict__ ctrlw, float* __restrict__ out) {
  const int i = blockIdx.x * 256 + threadIdx.x;
  if (i < 4480)
    __hip_atomic_store(ctrlw + i, 0u, __ATOMIC_RELAXED, __HIP_MEMORY_SCOPE_AGENT);
  if (i == 0) {
    __hip_atomic_store((u32*)out, 0u, __ATOMIC_RELAXED, __HIP_MEMORY_SCOPE_AGENT);
    const u64 rt = __builtin_amdgcn_s_memrealtime();
    __hip_atomic_store((u64*)(ctrlw + 4480), rt, __ATOMIC_RELAXED, __HIP_MEMORY_SCOPE_AGENT);
  }
}

// ---------------------------------------------------------------------------
// x2[t*64+b][e] = bf16(emb[sents[b][t]][e]).  One block per t.
__global__ __launch_bounds__(256) void k_embed(
    const int* __restrict__ sents, const float* __restrict__ emb,
    u16* __restrict__ x2) {
  __shared__ int tok[64];
  const int tid = threadIdx.x, t = blockIdx.x;
  if (tid < 64) tok[tid] = sents[tid * 512 + t];
  __syncthreads();
#pragma unroll
  for (int i = 0; i < 16; ++i) {
    const int v = i * 256 + tid;          // float4 index
    const int row = v >> 6, ke = (v & 63) * 4;
    const float4 f = *(const float4*)(emb + (size_t)tok[row] * 256 + ke);
    ushort4 s; s.x = f2b(f.x); s.y = f2b(f.y); s.z = f2b(f.z); s.w = f2b(f.w);
    *(ushort4*)&x2[((size_t)t * 64 + row) * 256 + ke] = s;
  }
}

// ---------------------------------------------------------------------------
// Persistent BiLSTM. 256 wgs x 256 thr, 1 wg/CU. group r=wid&7 -> (d=r>>2,
// g=r&3); slice s=wid>>3. Wave wv owns K-quarter for ALL 4 gates.
// Probe-validated sc0/L2 protocol or MALL fallback, chosen per group.
__global__ __launch_bounds__(256, 1) void k_lstm(
    const float* __restrict__ Whf, const float* __restrict__ Whb,
    const float* __restrict__ Wif, const float* __restrict__ Wib,
    const float* __restrict__ bf_, const float* __restrict__ bb_,
    const u16* __restrict__ x2, u16* __restrict__ H2, char* __restrict__ ctrl) {
  __shared__ float pre4[4096];          // [wv][gate][kh][lm][rr]
  __shared__ i64 ep_sh;
  __shared__ int fast_sh;
  const int tid = threadIdx.x, wid = blockIdx.x;
  const int r = wid & 7, d = r >> 2, g = r & 3, s = wid >> 3;
  const int b0 = g * 16, j0 = s * 16;
  const float* __restrict__ Whh = d ? Whb : Whf;
  const float* __restrict__ Wih = d ? Wib : Wif;
  const float* __restrict__ bias = d ? bb_ : bf_;
  const int wv = tid >> 6, lane = tid & 63, lm = lane & 15, kh = lane >> 4;
  const int bl = tid >> 4, jj = tid & 15;

  // epoch (k_init completed: stream order + dispatch-boundary release)
  if (tid == 0)
    ep_sh = (i64)__hip_atomic_load((u64*)(ctrl + 17920), __ATOMIC_RELAXED,
                                   __HIP_MEMORY_SCOPE_AGENT);
  __syncthreads();
  const i64 ep = ep_sh;

  // ---- coherence probe: does a peer's sc0 store become visible to my sc0
  // polls quickly? Tests the EXACT per-step mechanism. Group-consensus vote.
  if (tid == 0) {
    u64* prb = (u64*)(ctrl + 16384 + r * 64);
    u32* rep = (u32*)(ctrl + 16896 + r * 64);
    u32* bad = (u32*)(ctrl + 17408 + r * 64);
    const u64 sig = (u64)(ep + 1 + r);
    if (s == 0) st_u64s(prb, sig, false);       // leader: sc0 store
    int bud = 1 << 10;
    u64 v;
    do { v = ld_u64s(prb, false); } while (v != sig && --bud);
    if (v != sig)
      (void)__hip_atomic_fetch_add(bad, 1u, __ATOMIC_RELAXED, __HIP_MEMORY_SCOPE_AGENT);
    asm volatile("s_waitcnt vmcnt(0)" ::: "memory");  // bad visible before rep
    (void)__hip_atomic_fetch_add(rep, 1u, __ATOMIC_RELAXED, __HIP_MEMORY_SCOPE_AGENT);
    int bud2 = 1 << 20;
    u32 rv;
    do { rv = __hip_atomic_load(rep, __ATOMIC_RELAXED, __HIP_MEMORY_SCOPE_AGENT); }
    while (rv < 32 && --bud2);
    const u32 bv = __hip_atomic_load(bad, __ATOMIC_RELAXED, __HIP_MEMORY_SCOPE_AGENT);
    fast_sh = (rv >= 32 && bv == 0) ? 1 : 0;    // final-value consensus
  }
  __syncthreads();
  const bool mall = (fast_sh == 0);

  // ---- weight fragments: B[k][n], n=lane&15, k = kh*8+j + 32*kt + wv*Kq ----
  bf16x8 wih_f[8], whh_f[16];
#pragma unroll
  for (int gg = 0; gg < 4; ++gg) {
    const float* wp = Wih + (size_t)(gg * 512 + j0 + lm) * 256 + wv * 64;
#pragma unroll
    for (int kt = 0; kt < 2; ++kt) {
      bf16x8 f;
#pragma unroll
      for (int j = 0; j < 8; ++j) f[j] = (short)f2b(wp[kt * 32 + kh * 8 + j]);
      wih_f[gg * 2 + kt] = f;
    }
    const float* wq = Whh + (size_t)(gg * 512 + j0 + lm) * 512 + wv * 128;
#pragma unroll
    for (int kt = 0; kt < 4; ++kt) {
      bf16x8 f;
#pragma unroll
      for (int j = 0; j < 8; ++j) f[j] = (short)f2b(wq[kt * 32 + kh * 8 + j]);
      whh_f[gg * 4 + kt] = f;
    }
  }
  const float b_i = bias[0 * 512 + j0 + jj];
  const float b_f = bias[1 * 512 + j0 + jj];
  const float b_g = bias[2 * 512 + j0 + jj];
  const float b_o = bias[3 * 512 + j0 + jj];

  float c = 0.f;
  const f32x4 z = {0.f, 0.f, 0.f, 0.f};
#pragma unroll 1
  for (int it = 0; it < 512; ++it) {
    const int tt = d ? (511 - it) : it;
    // x a-frags (K-quarter): issue now, land during the poll
    bf16x8 xa[2];
    {
      const u16* xp = x2 + ((size_t)tt * 64 + b0 + lm) * 256 + wv * 64 + kh * 8;
      xa[0] = *(const bf16x8*)xp;
      xa[1] = *(const bf16x8*)(xp + 32);
    }
    if (it > 0) {
      const i64 tgt = ep + it;
      if (lane < 8) {       // wave-decoupled: poll only my 8 source slices
        const u64* fp = (const u64*)(ctrl + ((size_t)r * 32 + wv * 8 + lane) * 64);
        int bud = mall ? (1 << 10) : (1 << 12);
        i64 v;
        do { v = (i64)ld_u64s(fp, mall); } while (v < tgt && --bud);
      }
      asm volatile("" ::: "memory");    // no hoisting h loads above the poll
    }
    f32x4 accg[4] = {z, z, z, z};
#pragma unroll
    for (int gg = 0; gg < 4; ++gg)
#pragma unroll
      for (int kt = 0; kt < 2; ++kt)
        accg[gg] = __builtin_amdgcn_mfma_f32_16x16x32_bf16(xa[kt], wih_f[gg * 2 + kt], accg[gg], 0, 0, 0);
    if (it > 0) {
      const int tp = d ? (tt + 1) : (tt - 1);
      bf16x8 ha[4];
#pragma unroll
      for (int kt = 0; kt < 4; ++kt) {
        const int sG = wv * 8 + kt * 2 + (kh >> 1);
        const u16* hp = H2 + ((((size_t)tp * 2 + d) * 4 + g) * 32 + sG) * 256 + lm * 16 + (kh & 1) * 8;
        ha[kt] = *(const bf16x8*)hp;
      }
#pragma unroll
      for (int gg = 0; gg < 4; ++gg)
#pragma unroll
        for (int kt = 0; kt < 4; ++kt)
          accg[gg] = __builtin_amdgcn_mfma_f32_16x16x32_bf16(ha[kt], whh_f[gg * 4 + kt], accg[gg], 0, 0, 0);
    }
    // partials -> LDS, one ds_write_b128 per gate (layout [wv][g][kh][lm][rr])
#pragma unroll
    for (int gg = 0; gg < 4; ++gg)
      *(f32x4*)&pre4[wv * 1024 + gg * 256 + kh * 64 + lm * 4] = accg[gg];
    __syncthreads();
    const int off = (bl >> 2) * 64 + jj * 4 + (bl & 3);
    float pi = b_i, pf = b_f, pg = b_g, po = b_o;
#pragma unroll
    for (int w = 0; w < 4; ++w) {
      pi += pre4[w * 1024 + 0   + off];
      pf += pre4[w * 1024 + 256 + off];
      pg += pre4[w * 1024 + 512 + off];
      po += pre4[w * 1024 + 768 + off];
    }
    c = sigm(pf) * c + sigm(pi) * tanh_f(pg);
    const float h = sigm(po) * tanh_f(c);
    const float hq = __shfl_xor(h, 1);
    if ((tid & 1) == 0) {   // block element = tid; pack pair -> u32
      const u32 pk = (u32)f2b(h) | ((u32)f2b(hq) << 16);
      u32* hp2 = (u32*)H2 + ((((size_t)tt * 2 + d) * 4 + g) * 32 + s) * 128 + (tid >> 1);
      st_u32s(hp2, pk, mall);
    }
    asm volatile("s_waitcnt vmcnt(0)" ::: "memory");  // h acked before flag
    __syncthreads();
    if (tid == 0)
      st_u64s((u64*)(ctrl + ((size_t)r * 32 + s) * 64), (u64)(ep + it + 1), mall);
  }
}

// ---------------------------------------------------------------------------
// em[t*64+b][tag] = [hf|hb] @ W_out^T + b_out. One block per t; blocked-H2 A.
__global__ __launch_bounds__(256) void k_emproj(
    const u16* __restrict__ H2, const float* __restrict__ Wo,
    const float* __restrict__ bo, float* __restrict__ em) {
  __shared__ u16 Wl[32 * 1024];
  const int tid = threadIdx.x, mb = blockIdx.x;
  const int wv = tid >> 6, lane = tid & 63, lm = lane & 15, kh = lane >> 4;
#pragma unroll
  for (int i = 0; i < 32; ++i) {        // stage Wo 32x1024 f32 -> bf16, rotated
    const int row = i, k = tid * 4;
    const float4 f = *(const float4*)(Wo + (size_t)row * 1024 + k);
    ushort4 s; s.x = f2b(f.x); s.y = f2b(f.y); s.z = f2b(f.z); s.w = f2b(f.w);
    *(ushort4*)&Wl[row * 1024 + ((k + 8 * row) & 1023)] = s;
  }
  __syncthreads();
  const f32x4 z = {0.f, 0.f, 0.f, 0.f};
  f32x4 acc[2] = {z, z};
#pragma unroll 2
  for (int kt = 0; kt < 32; ++kt) {     // k-global = kt*32 + kh*8 + j
    const int dd = kt >> 4;
    const int sG = (kt & 15) * 2 + (kh >> 1);
    const u16* ap = H2 + ((((size_t)mb * 2 + dd) * 4 + wv) * 32 + sG) * 256 + lm * 16 + (kh & 1) * 8;
    const bf16x8 a = *(const bf16x8*)ap;
#pragma unroll
    for (int ni = 0; ni < 2; ++ni) {
      const int row = ni * 16 + lm;
      const bf16x8 b = *(const bf16x8*)&Wl[row * 1024 + ((kt * 32 + kh * 8 + 8 * row) & 1023)];
      acc[ni] = __builtin_amdgcn_mfma_f32_16x16x32_bf16(a, b, acc[ni], 0, 0, 0);
    }
  }
#pragma unroll
  for (int ni = 0; ni < 2; ++ni) {
    const int n = ni * 16 + lm;
    const float bv = bo[n];
#pragma unroll
    for (int rr = 0; rr < 4; ++rr) {
      const int m = mb * 64 + wv * 16 + kh * 4 + rr;
      em[(size_t)m * 32 + n] = acc[ni][rr] + bv;
    }
  }
}

// ---------------------------------------------------------------------------
// CRF forward scans, fp32. One wave per (b, which); halves merged via
// shfl_xor(32); t+1 prefetch; final reduction via atomicAdd(out).
__global__ __launch_bounds__(64) void k_crf(
    const float* __restrict__ em, const int* __restrict__ tgt,
    const float* __restrict__ trans, const float* __restrict__ stt,
    const float* __restrict__ ent, float* __restrict__ out) {
  __shared__ float trl[1024];
  __shared__ float al[32];
  __shared__ int cur[32];
  const int lane = threadIdx.x;
  const int b = blockIdx.x >> 1;
  const int isnum = blockIdx.x & 1;
#pragma unroll
  for (int i = 0; i < 16; ++i) trl[i * 64 + lane] = trans[i * 64 + lane];
  const int k = lane & 31, j0 = (lane >> 5) * 16;
  {
    float a0 = stt[k] + em[(size_t)b * 32 + k];
    int p0 = 1;
    if (isnum) { p0 = tgt[((size_t)b * 512) * 32 + k]; if (p0 == 0) a0 = IMPOSSIBLE; }
    if (lane < 32) { al[k] = a0; cur[k] = p0; }
  }
  __syncthreads();
  float emk = em[((size_t)64 + b) * 32 + k];                    // t=1 prefetch
  int tg = isnum ? tgt[((size_t)b * 512 + 1) * 32 + k] : 1;
#pragma unroll 1
  for (int t = 1; t < 512; ++t) {
    const float e_raw = emk;
    const int nxt = tg;
    if (t + 1 < 512) {                                          // prefetch t+1
      emk = em[((size_t)(t + 1) * 64 + b) * 32 + k];
      if (isnum) tg = tgt[((size_t)b * 512 + t + 1) * 32 + k];
    }
    const float e = (isnum && nxt == 0) ? IMPOSSIBLE : e_raw;
    float v[16];
    float m = -1e30f;
#pragma unroll
    for (int j = 0; j < 16; ++j) {
      float tr = trl[(j0 + j) * 32 + k];
      if (isnum && (cur[j0 + j] == 0 || nxt == 0)) tr = IMPOSSIBLE;
      v[j] = al[j0 + j] + tr;
      m = fmaxf(m, v[j]);
    }
    float ss = 0.f;
#pragma unroll
    for (int j = 0; j < 16; ++j) ss += __expf(v[j] - m);
    const float m2 = __shfl_xor(m, 32);
    const float s2 = __shfl_xor(ss, 32);
    const float M = fmaxf(m, m2);
    const float S = ss * __expf(m - M) + s2 * __expf(m2 - M);
    const float an = M + __logf(S) + e;
    __syncthreads();
    if (lane < 32) { al[k] = an; cur[k] = nxt; }
    __syncthreads();
  }
  float x;
  if (!isnum) {
    x = al[k] + ent[k];
  } else {
    const float et = ent[k] * (float)cur[k];
    x = al[k] + ((et == 0.f) ? IMPOSSIBLE : et);
  }
  float m = x;
#pragma unroll
  for (int o = 1; o < 32; o <<= 1) m = fmaxf(m, __shfl_xor(m, o));
  float ss = __expf(x - m);
#pragma unroll
  for (int o = 1; o < 32; o <<= 1) ss += __shfl_xor(ss, o);
  if (lane == 0) {
    const float rr = m + __logf(ss);
    atomicAdd(out, isnum ? -rr : rr);
  }
}

// ---------------------------------------------------------------------------
extern "C" void kernel_launch(void* const* d_in, const int* in_sizes, int n_in,
                              void* d_out, int out_size, void* d_ws, size_t ws_size,
                              hipStream_t stream) {
  (void)in_sizes; (void)n_in; (void)out_size; (void)ws_size;
  const int* sents = (const int*)d_in[0];
  const int* tgt = (const int*)d_in[2];
  const float* emb = (const float*)d_in[3];
  const float* Wif = (const float*)d_in[4];
  const float* Whf = (const float*)d_in[5];
  const float* bf_ = (const float*)d_in[6];
  const float* Wib = (const float*)d_in[7];
  const float* Whb = (const float*)d_in[8];
  const float* bb_ = (const float*)d_in[9];
  const float* Wo = (const float*)d_in[10];
  const float* bo = (const float*)d_in[11];
  const float* stt = (const float*)d_in[12];
  const float* ent = (const float*)d_in[13];
  const float* trans = (const float*)d_in[14];
  float* out = (float*)d_out;

  char* ws = (char*)d_ws;
  u16* x2 = (u16*)ws;                          // 16777216 B
  u16* H2 = (u16*)(ws + 16777216ull);          // 67108864 B (blocked)
  float* em = (float*)(ws + 83886080ull);      //  4194304 B
  char* ctrl = ws + 88080384ull;               //    17928 B

  k_init<<<dim3(18), dim3(256), 0, stream>>>((u32*)ctrl, out);
  k_embed<<<dim3(512), dim3(256), 0, stream>>>(sents, emb, x2);
  k_lstm<<<dim3(256), dim3(256), 0, stream>>>(Whf, Whb, Wif, Wib, bf_, bb_, x2, H2, ctrl);
  k_emproj<<<dim3(512), dim3(256), 0, stream>>>(H2, Wo, bo, em);
  k_crf<<<dim3(128), dim3(64), 0, stream>>>(em, tgt, trans, stt, ent, out);
}

// Round 7
// 1827.412 us; speedup vs baseline: 474.3795x; 119.3708x over previous
//
#include <hip/hip_runtime.h>

// BiLSTM + partial-CRF loss, MI355X (gfx950).
// R7: single proven sync path. R6's sc0/probe fast path never propagated
// per-step flags (poll budget burned every step -> 250ms). R7 = R3's
// measured-good MALL protocol (agent-scope atomics, u32 flags, detect <10
// polls) + R6's validated structure: K-split across waves (h reads 16KB not
// 64KB per wg/step), blocked H2 (one contiguous 512B block per slice/step),
// ds_write_b128 LDS partial sums, x-frag loads issued before the poll.
//
// Sizes: B=64, L=512, V=50000, E=256, H=512, T=32.
// Workspace (~84 MiB):
//   x2   bf16 [512*64][256]                16777216 B @ 0
//   H2   bf16 blocked [t][d][g][s][256]    67108864 B @ 16777216
//   em   f32  [512*64][32]                  4194304 B @ 83886080
//   flg  u32  [8 groups][32 slices] 64B apart, 16384 B @ 88080384

#define IMPOSSIBLE -10000.0f

typedef __attribute__((ext_vector_type(8))) short bf16x8;
typedef __attribute__((ext_vector_type(4))) float f32x4;
typedef unsigned int u32;
typedef unsigned short u16;

__device__ __forceinline__ u16 f2b(float f) {           // fp32 -> bf16 (RNE)
  union { float f; u32 u; } v; v.f = f;
  return (u16)((v.u + 0x7fffu + ((v.u >> 16) & 1u)) >> 16);
}
__device__ __forceinline__ float sigm(float x) { return 1.0f / (1.0f + __expf(-x)); }
__device__ __forceinline__ float tanh_f(float x) { return 1.0f - 2.0f / (__expf(2.0f * x) + 1.0f); }

// ---------------------------------------------------------------------------
// flags=0 + out=0, MALL-visible stores (same mechanism the polls use).
__global__ void k_init(u32* __restrict__ flg, float* __restrict__ out) {
  const int i = blockIdx.x * 256 + threadIdx.x;
  if (i < 4096)
    __hip_atomic_store(flg + i, 0u, __ATOMIC_RELAXED, __HIP_MEMORY_SCOPE_AGENT);
  if (i == 4096)
    __hip_atomic_store((u32*)out, 0u, __ATOMIC_RELAXED, __HIP_MEMORY_SCOPE_AGENT);
}

// ---------------------------------------------------------------------------
// x2[t*64+b][e] = bf16(emb[sents[b][t]][e]).  One block per t.
__global__ __launch_bounds__(256) void k_embed(
    const int* __restrict__ sents, const float* __restrict__ emb,
    u16* __restrict__ x2) {
  __shared__ int tok[64];
  const int tid = threadIdx.x, t = blockIdx.x;
  if (tid < 64) tok[tid] = sents[tid * 512 + t];
  __syncthreads();
#pragma unroll
  for (int i = 0; i < 16; ++i) {
    const int v = i * 256 + tid;          // float4 index
    const int row = v >> 6, ke = (v & 63) * 4;
    const float4 f = *(const float4*)(emb + (size_t)tok[row] * 256 + ke);
    ushort4 s; s.x = f2b(f.x); s.y = f2b(f.y); s.z = f2b(f.z); s.w = f2b(f.w);
    *(ushort4*)&x2[((size_t)t * 64 + row) * 256 + ke] = s;
  }
}

// ---------------------------------------------------------------------------
// Persistent BiLSTM. 256 wgs x 256 thr, 1 wg/CU. group r=wid&7 -> (d=r>>2,
// g=r&3); slice s=wid>>3 (j0=s*16). Wave wv owns K-quarter for ALL 4 gates.
// Per step: issue x loads -> per-wave poll of its 8 source-slice flags
// (agent atomics, R3-proven) -> x+h MFMAs (h via plain b128 from blocked H2;
// lines are t-specific so first read is always fresh) -> ds_write_b128
// partials -> barrier -> 4-way reduce + gates -> packed agent h store ->
// vmcnt drain + barrier -> tid0 agent flag store (it+1).
__global__ __launch_bounds__(256, 1) void k_lstm(
    const float* __restrict__ Whf, const float* __restrict__ Whb,
    const float* __restrict__ Wif, const float* __restrict__ Wib,
    const float* __restrict__ bf_, const float* __restrict__ bb_,
    const u16* __restrict__ x2, u16* __restrict__ H2, u32* __restrict__ flg) {
  __shared__ float pre4[4096];          // [wv][gate][kh][lm][rr]
  const int tid = threadIdx.x, wid = blockIdx.x;
  const int r = wid & 7, d = r >> 2, g = r & 3, s = wid >> 3;
  const int b0 = g * 16, j0 = s * 16;
  const float* __restrict__ Whh = d ? Whb : Whf;
  const float* __restrict__ Wih = d ? Wib : Wif;
  const float* __restrict__ bias = d ? bb_ : bf_;
  const int wv = tid >> 6, lane = tid & 63, lm = lane & 15, kh = lane >> 4;
  const int bl = tid >> 4, jj = tid & 15;

  // ---- weight fragments: B[k][n], n=lane&15, k = kh*8+j + 32*kt + wv*Kq ----
  bf16x8 wih_f[8], whh_f[16];
#pragma unroll
  for (int gg = 0; gg < 4; ++gg) {
    const float* wp = Wih + (size_t)(gg * 512 + j0 + lm) * 256 + wv * 64;
#pragma unroll
    for (int kt = 0; kt < 2; ++kt) {
      bf16x8 f;
#pragma unroll
      for (int j = 0; j < 8; ++j) f[j] = (short)f2b(wp[kt * 32 + kh * 8 + j]);
      wih_f[gg * 2 + kt] = f;
    }
    const float* wq = Whh + (size_t)(gg * 512 + j0 + lm) * 512 + wv * 128;
#pragma unroll
    for (int kt = 0; kt < 4; ++kt) {
      bf16x8 f;
#pragma unroll
      for (int j = 0; j < 8; ++j) f[j] = (short)f2b(wq[kt * 32 + kh * 8 + j]);
      whh_f[gg * 4 + kt] = f;
    }
  }
  const float b_i = bias[0 * 512 + j0 + jj];
  const float b_f = bias[1 * 512 + j0 + jj];
  const float b_g = bias[2 * 512 + j0 + jj];
  const float b_o = bias[3 * 512 + j0 + jj];

  u32* gflg = flg + (size_t)r * 512;    // 32 flags, 16 u32 (64B) apart
  float c = 0.f;
  const f32x4 z = {0.f, 0.f, 0.f, 0.f};
#pragma unroll 1
  for (int it = 0; it < 512; ++it) {
    const int tt = d ? (511 - it) : it;
    // x a-frags (K-quarter): issue now, land during the poll
    bf16x8 xa[2];
    {
      const u16* xp = x2 + ((size_t)tt * 64 + b0 + lm) * 256 + wv * 64 + kh * 8;
      xa[0] = *(const bf16x8*)xp;
      xa[1] = *(const bf16x8*)(xp + 32);
    }
    if (it > 0) {
      if (lane < 8) {       // wave-decoupled: poll only my 8 source slices
        const u32* fp = gflg + (wv * 8 + lane) * 16;
        int bud = 1 << 16;  // normal detect <10 polls (R3-measured)
        while (__hip_atomic_load(fp, __ATOMIC_RELAXED, __HIP_MEMORY_SCOPE_AGENT) <
                   (u32)it && --bud) {}
      }
      asm volatile("" ::: "memory");    // no hoisting h loads above the poll
    }
    f32x4 accg[4] = {z, z, z, z};
#pragma unroll
    for (int gg = 0; gg < 4; ++gg)
#pragma unroll
      for (int kt = 0; kt < 2; ++kt)
        accg[gg] = __builtin_amdgcn_mfma_f32_16x16x32_bf16(xa[kt], wih_f[gg * 2 + kt], accg[gg], 0, 0, 0);
    if (it > 0) {
      const int tp = d ? (tt + 1) : (tt - 1);
      bf16x8 ha[4];
#pragma unroll
      for (int kt = 0; kt < 4; ++kt) {
        const int sG = wv * 8 + kt * 2 + (kh >> 1);
        const u16* hp = H2 + ((((size_t)tp * 2 + d) * 4 + g) * 32 + sG) * 256 + lm * 16 + (kh & 1) * 8;
        ha[kt] = *(const bf16x8*)hp;
      }
#pragma unroll
      for (int gg = 0; gg < 4; ++gg)
#pragma unroll
        for (int kt = 0; kt < 4; ++kt)
          accg[gg] = __builtin_amdgcn_mfma_f32_16x16x32_bf16(ha[kt], whh_f[gg * 4 + kt], accg[gg], 0, 0, 0);
    }
    // partials -> LDS, one ds_write_b128 per gate (layout [wv][g][kh][lm][rr])
#pragma unroll
    for (int gg = 0; gg < 4; ++gg)
      *(f32x4*)&pre4[wv * 1024 + gg * 256 + kh * 64 + lm * 4] = accg[gg];
    __syncthreads();
    const int off = (bl >> 2) * 64 + jj * 4 + (bl & 3);
    float pi = b_i, pf = b_f, pg = b_g, po = b_o;
#pragma unroll
    for (int w = 0; w < 4; ++w) {
      pi += pre4[w * 1024 + 0   + off];
      pf += pre4[w * 1024 + 256 + off];
      pg += pre4[w * 1024 + 512 + off];
      po += pre4[w * 1024 + 768 + off];
    }
    c = sigm(pf) * c + sigm(pi) * tanh_f(pg);
    const float h = sigm(po) * tanh_f(c);
    const float hq = __shfl_xor(h, 1);
    if ((tid & 1) == 0) {   // block element = tid; pack pair -> u32, agent store
      const u32 pk = (u32)f2b(h) | ((u32)f2b(hq) << 16);
      u32* hp2 = (u32*)H2 + ((((size_t)tt * 2 + d) * 4 + g) * 32 + s) * 128 + (tid >> 1);
      __hip_atomic_store(hp2, pk, __ATOMIC_RELAXED, __HIP_MEMORY_SCOPE_AGENT);
    }
    asm volatile("s_waitcnt vmcnt(0)" ::: "memory");  // h acked at MALL
    __syncthreads();                                  // => all waves drained
    if (tid == 0)
      __hip_atomic_store(gflg + s * 16, (u32)(it + 1), __ATOMIC_RELAXED,
                         __HIP_MEMORY_SCOPE_AGENT);
  }
}

// ---------------------------------------------------------------------------
// em[t*64+b][tag] = [hf|hb] @ W_out^T + b_out. One block per t; blocked-H2 A.
__global__ __launch_bounds__(256) void k_emproj(
    const u16* __restrict__ H2, const float* __restrict__ Wo,
    const float* __restrict__ bo, float* __restrict__ em) {
  __shared__ u16 Wl[32 * 1024];
  const int tid = threadIdx.x, mb = blockIdx.x;
  const int wv = tid >> 6, lane = tid & 63, lm = lane & 15, kh = lane >> 4;
#pragma unroll
  for (int i = 0; i < 32; ++i) {        // stage Wo 32x1024 f32 -> bf16, rotated
    const int row = i, k = tid * 4;
    const float4 f = *(const float4*)(Wo + (size_t)row * 1024 + k);
    ushort4 s; s.x = f2b(f.x); s.y = f2b(f.y); s.z = f2b(f.z); s.w = f2b(f.w);
    *(ushort4*)&Wl[row * 1024 + ((k + 8 * row) & 1023)] = s;
  }
  __syncthreads();
  const f32x4 z = {0.f, 0.f, 0.f, 0.f};
  f32x4 acc[2] = {z, z};
#pragma unroll 2
  for (int kt = 0; kt < 32; ++kt) {     // k-global = kt*32 + kh*8 + j
    const int dd = kt >> 4;
    const int sG = (kt & 15) * 2 + (kh >> 1);
    const u16* ap = H2 + ((((size_t)mb * 2 + dd) * 4 + wv) * 32 + sG) * 256 + lm * 16 + (kh & 1) * 8;
    const bf16x8 a = *(const bf16x8*)ap;
#pragma unroll
    for (int ni = 0; ni < 2; ++ni) {
      const int row = ni * 16 + lm;
      const bf16x8 b = *(const bf16x8*)&Wl[row * 1024 + ((kt * 32 + kh * 8 + 8 * row) & 1023)];
      acc[ni] = __builtin_amdgcn_mfma_f32_16x16x32_bf16(a, b, acc[ni], 0, 0, 0);
    }
  }
#pragma unroll
  for (int ni = 0; ni < 2; ++ni) {
    const int n = ni * 16 + lm;
    const float bv = bo[n];
#pragma unroll
    for (int rr = 0; rr < 4; ++rr) {
      const int m = mb * 64 + wv * 16 + kh * 4 + rr;
      em[(size_t)m * 32 + n] = acc[ni][rr] + bv;
    }
  }
}

// ---------------------------------------------------------------------------
// CRF forward scans, fp32. One wave per (b, which); halves merged via
// shfl_xor(32); t+1 prefetch; final reduction via atomicAdd(out).
__global__ __launch_bounds__(64) void k_crf(
    const float* __restrict__ em, const int* __restrict__ tgt,
    const float* __restrict__ trans, const float* __restrict__ stt,
    const float* __restrict__ ent, float* __restrict__ out) {
  __shared__ float trl[1024];
  __shared__ float al[32];
  __shared__ int cur[32];
  const int lane = threadIdx.x;
  const int b = blockIdx.x >> 1;
  const int isnum = blockIdx.x & 1;
#pragma unroll
  for (int i = 0; i < 16; ++i) trl[i * 64 + lane] = trans[i * 64 + lane];
  const int k = lane & 31, j0 = (lane >> 5) * 16;
  {
    float a0 = stt[k] + em[(size_t)b * 32 + k];
    int p0 = 1;
    if (isnum) { p0 = tgt[((size_t)b * 512) * 32 + k]; if (p0 == 0) a0 = IMPOSSIBLE; }
    if (lane < 32) { al[k] = a0; cur[k] = p0; }
  }
  __syncthreads();
  float emk = em[((size_t)64 + b) * 32 + k];                    // t=1 prefetch
  int tg = isnum ? tgt[((size_t)b * 512 + 1) * 32 + k] : 1;
#pragma unroll 1
  for (int t = 1; t < 512; ++t) {
    const float e_raw = emk;
    const int nxt = tg;
    if (t + 1 < 512) {                                          // prefetch t+1
      emk = em[((size_t)(t + 1) * 64 + b) * 32 + k];
      if (isnum) tg = tgt[((size_t)b * 512 + t + 1) * 32 + k];
    }
    const float e = (isnum && nxt == 0) ? IMPOSSIBLE : e_raw;
    float v[16];
    float m = -1e30f;
#pragma unroll
    for (int j = 0; j < 16; ++j) {
      float tr = trl[(j0 + j) * 32 + k];
      if (isnum && (cur[j0 + j] == 0 || nxt == 0)) tr = IMPOSSIBLE;
      v[j] = al[j0 + j] + tr;
      m = fmaxf(m, v[j]);
    }
    float ss = 0.f;
#pragma unroll
    for (int j = 0; j < 16; ++j) ss += __expf(v[j] - m);
    const float m2 = __shfl_xor(m, 32);
    const float s2 = __shfl_xor(ss, 32);
    const float M = fmaxf(m, m2);
    const float S = ss * __expf(m - M) + s2 * __expf(m2 - M);
    const float an = M + __logf(S) + e;
    __syncthreads();
    if (lane < 32) { al[k] = an; cur[k] = nxt; }
    __syncthreads();
  }
  float x;
  if (!isnum) {
    x = al[k] + ent[k];
  } else {
    const float et = ent[k] * (float)cur[k];
    x = al[k] + ((et == 0.f) ? IMPOSSIBLE : et);
  }
  float m = x;
#pragma unroll
  for (int o = 1; o < 32; o <<= 1) m = fmaxf(m, __shfl_xor(m, o));
  float ss = __expf(x - m);
#pragma unroll
  for (int o = 1; o < 32; o <<= 1) ss += __shfl_xor(ss, o);
  if (lane == 0) {
    const float rr = m + __logf(ss);
    atomicAdd(out, isnum ? -rr : rr);
  }
}

// ---------------------------------------------------------------------------
extern "C" void kernel_launch(void* const* d_in, const int* in_sizes, int n_in,
                              void* d_out, int out_size, void* d_ws, size_t ws_size,
                              hipStream_t stream) {
  (void)in_sizes; (void)n_in; (void)out_size; (void)ws_size;
  const int* sents = (const int*)d_in[0];
  const int* tgt = (const int*)d_in[2];
  const float* emb = (const float*)d_in[3];
  const float* Wif = (const float*)d_in[4];
  const float* Whf = (const float*)d_in[5];
  const float* bf_ = (const float*)d_in[6];
  const float* Wib = (const float*)d_in[7];
  const float* Whb = (const float*)d_in[8];
  const float* bb_ = (const float*)d_in[9];
  const float* Wo = (const float*)d_in[10];
  const float* bo = (const float*)d_in[11];
  const float* stt = (const float*)d_in[12];
  const float* ent = (const float*)d_in[13];
  const float* trans = (const float*)d_in[14];
  float* out = (float*)d_out;

  char* ws = (char*)d_ws;
  u16* x2 = (u16*)ws;                          // 16777216 B
  u16* H2 = (u16*)(ws + 16777216ull);          // 67108864 B (blocked)
  float* em = (float*)(ws + 83886080ull);      //  4194304 B
  u32* flg = (u32*)(ws + 88080384ull);         //    16384 B

  k_init<<<dim3(17), dim3(256), 0, stream>>>(flg, out);
  k_embed<<<dim3(512), dim3(256), 0, stream>>>(sents, emb, x2);
  k_lstm<<<dim3(256), dim3(256), 0, stream>>>(Whf, Whb, Wif, Wib, bf_, bb_, x2, H2, flg);
  k_emproj<<<dim3(512), dim3(256), 0, stream>>>(H2, Wo, bo, em);
  k_crf<<<dim3(128), dim3(64), 0, stream>>>(em, tgt, trans, stt, ent, out);
}